// Round 7
// baseline (523.931 us; speedup 1.0000x reference)
//
#include <hip/hip_runtime.h>

// Problem constants
#define BTOT 16384
#define NI   16
#define HD   256
#define BB   4            // elements per block = waves per block
#define NMID 3
#define ASH  264          // h LDS row stride in bf16 (528B, 16B-aligned, bank-spread)
#define SLS  20           // slater scratch row stride (floats)
#define NCHUNK 49         // 48 mid chunks + 1 slater chunk
#define HALF_LOGFACT 15.3359295387f  // 0.5 * ln(16!)

typedef short  bf16x8 __attribute__((ext_vector_type(8)));
typedef float  f32x4  __attribute__((ext_vector_type(4)));
typedef const __attribute__((address_space(1))) unsigned int* as1p;
typedef __attribute__((address_space(3))) unsigned int* as3p;

__device__ __forceinline__ unsigned short f2bf(float f) {
    unsigned u = __builtin_bit_cast(unsigned, f);
    u += 0x7FFFu + ((u >> 16) & 1u);          // RNE
    return (unsigned short)(u >> 16);
}
__device__ __forceinline__ float bf2f(unsigned short h) {
    return __builtin_bit_cast(float, (unsigned)h << 16);
}
// tanh(x) = 1 - 2/(1 + 2^(x*2*log2(e))) : 5 VALU ops, exact at +/-inf
__device__ __forceinline__ float tanh5(float x) {
    float z = __builtin_amdgcn_exp2f(x * 2.885390081777927f);
    return __builtin_fmaf(-2.0f, __builtin_amdgcn_rcpf(1.0f + z), 1.0f);
}

// ---- prep: chunked fragment-order weights (verified R6).
// Chunk fc<48: (layer=fc>>4, ch=fc&15): dst[kg*128 + j*8 + kk] = Wmid[layer][8kg+kk][ch*16+j],
//   kg in [0,64). Chunk 48: Wsl, kg in [0,32), rest zero.
__global__ void prep_w(const float* __restrict__ Wmid, const float* __restrict__ Wsl,
                       unsigned short* __restrict__ wtc) {
    const int b = blockIdx.x;       // 0..48
    const int t = threadIdx.x;
    unsigned short* dst = wtc + (size_t)b * 8192;
    if (b < 48) {
        const int layer = b >> 4, ch = b & 15;
        const float* src = Wmid + (size_t)layer * (2 * HD * HD);
#pragma unroll 4
        for (int v = 0; v < 32; ++v) {
            int o = t * 32 + v;
            int kk = o & 7, j = (o >> 3) & 15, kg = o >> 7;
            dst[o] = f2bf(src[(8 * kg + kk) * HD + ch * 16 + j]);
        }
    } else {
#pragma unroll 4
        for (int v = 0; v < 32; ++v) {
            int o = t * 32 + v;
            int kk = o & 7, j = (o >> 3) & 15, kg = o >> 7;
            dst[o] = (kg < 32) ? f2bf(Wsl[(8 * kg + kk) * NI + j]) : (unsigned short)0;
        }
    }
}

struct __align__(16) SMem {
    unsigned short wtile[8192];           // 16384 B: staged W chunk [kg][16 j][8 k]
    union {
        unsigned short h[BB * NI * ASH];  // 33792 B: bf16 h (in-place across layers)
        float slf[BB][NI * ASH / 2];      // per-element slater scratch (own region)
    } u;
    unsigned short gm[BB * HD];           // 2048 B: bf16 column means per element
    union {
        unsigned short gv[BB * HD];       // 2048 B: bf16 gvec (mid layers)
        struct { float x0[BB * NI]; float gmean[BB]; } x;  // input phase only
    } v;
};
static_assert(sizeof(SMem) == 54272, "LDS budget: 3 blocks/CU needs <= 54613 B");

__global__ __launch_bounds__(256, 3)
void eqslater_mfma(const float* __restrict__ x0g,
                   const float* __restrict__ Win,
                   const float* __restrict__ bin,
                   const float* __restrict__ bmid,
                   const float* __restrict__ bsl,
                   const float* __restrict__ width,
                   const unsigned short* __restrict__ wtc,
                   float* __restrict__ out) {
    __shared__ SMem sm;
    const int tid = threadIdx.x;
    const int bbase = blockIdx.x * BB;
    const int e = tid >> 6;   // wave = element
    const int l = tid & 63;
    const int c = l & 15;     // A-row / B-col / C-col
    const int g = l >> 4;     // k-group

    if (tid < BB * NI) sm.v.x.x0[tid] = x0g[bbase * NI + tid];
    __syncthreads();
    if (tid < BB) {
        float s = 0.f;
#pragma unroll
        for (int n = 0; n < NI; ++n) s += sm.v.x.x0[tid * NI + n];
        sm.v.x.gmean[tid] = s * 0.0625f;
    }
    __syncthreads();

    // ---- input layer (fp32 VALU): h = tanh(x0*W0 + g*W1 + b), stored bf16
    {
        const int j = tid;
        const float w0 = Win[j], w1 = Win[HD + j], bj = bin[j];
#pragma unroll 4
        for (int r = 0; r < BB * NI; ++r) {
            float pre = fmaf(sm.v.x.x0[r], w0, fmaf(sm.v.x.gmean[r >> 4], w1, bj));
            sm.u.h[r * ASH + j] = f2bf(tanh5(pre));
        }
    }
    __syncthreads();   // h visible; x0/gmean dead -> gv region reusable

    bf16x8 af[8], agm[8];

#pragma unroll 1
    for (int layer = 0; layer < NMID; ++layer) {
        // ---- gm: column means of own h (wave-private write)
        {
            const int c0 = l * 4;
            float s0 = 0, s1 = 0, s2 = 0, s3 = 0;
#pragma unroll
            for (int r = 0; r < NI; ++r) {
                short4 vq = *(const short4*)&sm.u.h[(e * NI + r) * ASH + c0];
                s0 += bf2f((unsigned short)vq.x);
                s1 += bf2f((unsigned short)vq.y);
                s2 += bf2f((unsigned short)vq.z);
                s3 += bf2f((unsigned short)vq.w);
            }
            short4 o;
            o.x = (short)f2bf(s0 * 0.0625f); o.y = (short)f2bf(s1 * 0.0625f);
            o.z = (short)f2bf(s2 * 0.0625f); o.w = (short)f2bf(s3 * 0.0625f);
            *(short4*)&sm.gm[e * HD + c0] = o;
        }
        // ---- A fragments: own h rows (k<256). Held in regs across all chunks.
#pragma unroll
        for (int s = 0; s < 8; ++s)
            af[s] = *(const bf16x8*)&sm.u.h[(e * NI + c) * ASH + 32 * s + 8 * g];

        const float* bml = bmid + layer * HD;
        f32x4 avp = {0.f, 0.f, 0.f, 0.f};
        float biasp = 0.f;

#pragma unroll 1
        for (int ch = 0; ch < 16; ++ch) {
            __syncthreads();   // (A) all waves done reading wtile(prev)
            {   // async stage chunk layer*16+ch -> wtile (linear, width=16)
                const unsigned short* gsrc = wtc + (size_t)(layer * 16 + ch) * 8192 + tid * 8;
#pragma unroll
                for (int p = 0; p < 4; ++p)
                    __builtin_amdgcn_global_load_lds((as1p)(gsrc + p * 2048),
                                                     (as3p)(sm.wtile + tid * 8 + p * 2048),
                                                     16, 0, 0);
            }
            if (ch == 0) {   // (A) ordered all waves' gm writes; build replicated-gm A frags
#pragma unroll
                for (int s = 0; s < 8; ++s)
                    agm[s] = *(const bf16x8*)&sm.gm[(c & 3) * HD + 32 * s + 8 * g];
            }
            const float biasc = bml[ch * 16 + c];
            __syncthreads();   // (B) wtile ready (syncthreads drains vmcnt)

            // ---- h-part GEMM: 8 MFMA, K=0..255
            f32x4 p0 = {0.f,0.f,0.f,0.f}, p1 = {0.f,0.f,0.f,0.f};
#pragma unroll
            for (int s = 0; s < 4; ++s) {
                bf16x8 b0 = *(const bf16x8*)&sm.wtile[(4 * (2 * s)     + g) * 128 + c * 8];
                bf16x8 b1 = *(const bf16x8*)&sm.wtile[(4 * (2 * s + 1) + g) * 128 + c * 8];
                p0 = __builtin_amdgcn_mfma_f32_16x16x32_bf16(af[2 * s],     b0, p0, 0, 0, 0);
                p1 = __builtin_amdgcn_mfma_f32_16x16x32_bf16(af[2 * s + 1], b1, p1, 0, 0, 0);
            }
            f32x4 avc = p0 + p1;

            // ---- rank-1 gm-GEMM: owner wave computes gvec for ALL 4 elements
            if ((ch >> 2) == e) {
                f32x4 q0 = {0.f,0.f,0.f,0.f}, q1 = {0.f,0.f,0.f,0.f};
#pragma unroll
                for (int s = 0; s < 4; ++s) {
                    bf16x8 b2 = *(const bf16x8*)&sm.wtile[(32 + 4 * (2 * s)     + g) * 128 + c * 8];
                    bf16x8 b3 = *(const bf16x8*)&sm.wtile[(32 + 4 * (2 * s + 1) + g) * 128 + c * 8];
                    q0 = __builtin_amdgcn_mfma_f32_16x16x32_bf16(agm[2 * s],     b2, q0, 0, 0, 0);
                    q1 = __builtin_amdgcn_mfma_f32_16x16x32_bf16(agm[2 * s + 1], b3, q1, 0, 0, 0);
                }
                f32x4 gq = q0 + q1;   // reg q == gvec[el=q][16ch+c] (rows replicate mod 4)
                float wv = (g == 0) ? gq[0] : (g == 1) ? gq[1] : (g == 2) ? gq[2] : gq[3];
                sm.v.gv[g * HD + ch * 16 + c] = f2bf(wv);
            }

            // ---- lagged epilogue for chunk ch-1 (gvec(ch-1) visible via (A)+(B))
            if (ch > 0) {
                const int j = (ch - 1) * 16 + c;
                const float gvv = bf2f(sm.v.gv[e * HD + j]);
#pragma unroll
                for (int q = 0; q < 4; ++q) {
                    const int hidx = (e * NI + 4 * g + q) * ASH + j;
                    float o = tanh5(avp[q] + gvv + biasp) + bf2f(sm.u.h[hidx]);
                    sm.u.h[hidx] = f2bf(o);
                }
            }
            avp = avc; biasp = biasc;
        }
        __syncthreads();   // (E) gvec(15) from owner wave visible
        {   // final epilogue of the layer
            const int j = 15 * 16 + c;
            const float gvv = bf2f(sm.v.gv[e * HD + j]);
#pragma unroll
            for (int q = 0; q < 4; ++q) {
                const int hidx = (e * NI + 4 * g + q) * ASH + j;
                float o = tanh5(avp[q] + gvv + biasp) + bf2f(sm.u.h[hidx]);
                sm.u.h[hidx] = f2bf(o);
            }
        }
    }

    // ---- stage slater chunk (all waves past (E): wtile reads done); hide under af-reload
    {
        const unsigned short* gsrc = wtc + (size_t)48 * 8192 + tid * 8;
#pragma unroll
        for (int p = 0; p < 4; ++p)
            __builtin_amdgcn_global_load_lds((as1p)(gsrc + p * 2048),
                                             (as3p)(sm.wtile + tid * 8 + p * 2048),
                                             16, 0, 0);
    }
#pragma unroll
    for (int s = 0; s < 8; ++s)
        af[s] = *(const bf16x8*)&sm.u.h[(e * NI + c) * ASH + 32 * s + 8 * g];
    __syncthreads();   // slater wtile ready

    // ---- slater head: 16x16 = h(16x256) @ Wsl + bsl, 8 MFMA
    {
        f32x4 a0 = {0.f,0.f,0.f,0.f}, a1 = {0.f,0.f,0.f,0.f};
#pragma unroll
        for (int s = 0; s < 4; ++s) {
            bf16x8 b0 = *(const bf16x8*)&sm.wtile[(4 * (2 * s)     + g) * 128 + c * 8];
            bf16x8 b1 = *(const bf16x8*)&sm.wtile[(4 * (2 * s + 1) + g) * 128 + c * 8];
            a0 = __builtin_amdgcn_mfma_f32_16x16x32_bf16(af[2 * s],     b0, a0, 0, 0, 0);
            a1 = __builtin_amdgcn_mfma_f32_16x16x32_bf16(af[2 * s + 1], b1, a1, 0, 0, 0);
        }
        f32x4 sv = a0 + a1;
        const float bs = bsl[c];
        float* slp = &sm.u.slf[e][0];   // own-element region; own h now dead
#pragma unroll
        for (int q = 0; q < 4; ++q)
            slp[(4 * g + q) * SLS + c] = sv[q] + bs;
    }

    // ---- per-wave slogdet: register LU w/ partial pivoting (R4-verified)
    {
        const float* slp = &sm.u.slf[e][0];
        const int i = c;   // row, 4x duplicated across lanes
        float M[16];
#pragma unroll
        for (int jj = 0; jj < 4; ++jj) {
            float4 vv = *(const float4*)&slp[i * SLS + 4 * jj];
            M[4 * jj] = vv.x; M[4 * jj + 1] = vv.y; M[4 * jj + 2] = vv.z; M[4 * jj + 3] = vv.w;
        }

        float dsign = 1.f, logabs = 0.f;
#pragma unroll
        for (int k = 0; k < 16; ++k) {
            float myv = (i >= k) ? __builtin_fabsf(M[k]) : -1.f;
            float maxv = myv;
#pragma unroll
            for (int off = 32; off > 0; off >>= 1)
                maxv = fmaxf(maxv, __shfl_xor(maxv, off));
            unsigned long long bal = __ballot(myv == maxv);
            int p = (__ffsll((long long)bal) - 1) & 15;

            if (p != k) {
                dsign = -dsign;
#pragma unroll
                for (int j = 0; j < 16; ++j) {
                    float vk = __shfl(M[j], k);
                    float vp = __shfl(M[j], p);
                    if (i == k) M[j] = vp;
                    if (i == p) M[j] = vk;
                }
            }
            float piv = __shfl(M[k], k);
            // NaN guard (singular matrix): finite logabs, no 0/0 poison.
            float ap = fmaxf(__builtin_fabsf(piv), 1e-35f);
            logabs += __logf(ap);
            if (piv < 0.f) dsign = -dsign;
            float spiv = __builtin_copysignf(ap, piv);
            float mi = __fdividef(M[k], spiv);
#pragma unroll
            for (int j = k + 1; j < 16; ++j) {
                float vkj = __shfl(M[j], k);
                if (i > k) M[j] = __builtin_fmaf(-mi, vkj, M[j]);
            }
        }

        float xv = (l < NI) ? x0g[(bbase + e) * NI + l] : 0.f;
        float sq = xv * xv;
#pragma unroll
        for (int off = 8; off > 0; off >>= 1) sq += __shfl_xor(sq, off);

        if (l == 0) {
            out[bbase + e] = dsign;
            out[BTOT + bbase + e] = logabs - HALF_LOGFACT - width[0] * sq;
        }
    }
}

extern "C" void kernel_launch(void* const* d_in, const int* in_sizes, int n_in,
                              void* d_out, int out_size, void* d_ws, size_t ws_size,
                              hipStream_t stream) {
    const float* x0   = (const float*)d_in[0];
    const float* Win  = (const float*)d_in[1];
    const float* bin  = (const float*)d_in[2];
    const float* Wmid = (const float*)d_in[3];
    const float* bmid = (const float*)d_in[4];
    const float* Wsl  = (const float*)d_in[5];
    const float* bsl  = (const float*)d_in[6];
    const float* wid  = (const float*)d_in[7];
    float* out = (float*)d_out;

    unsigned short* wtc = (unsigned short*)d_ws;   // 49 * 16384 B = 802816 B

    hipLaunchKernelGGL(prep_w, dim3(NCHUNK), dim3(256), 0, stream, Wmid, Wsl, wtc);
    hipLaunchKernelGGL(eqslater_mfma, dim3(BTOT / BB), dim3(256), 0, stream,
                       x0, Win, bin, bmid, bsl, wid, wtc, out);
}

// Round 8
// 477.054 us; speedup vs baseline: 1.0983x; 1.0983x over previous
//
#include <hip/hip_runtime.h>

// Problem constants
#define BTOT 16384
#define NI   16
#define HD   256
#define BB   4            // elements per block = waves per block
#define NMID 3
#define ASH  264          // h LDS row stride in bf16 (528B, 16B-aligned, bank-spread)
#define SLS  20           // slater scratch row stride (floats)
#define HALF_LOGFACT 15.3359295387f  // 0.5 * ln(16!)

typedef short  bf16x8 __attribute__((ext_vector_type(8)));
typedef float  f32x4  __attribute__((ext_vector_type(4)));
typedef const __attribute__((address_space(1))) unsigned int* as1p;
typedef __attribute__((address_space(3))) unsigned int* as3p;

__device__ __forceinline__ unsigned short f2bf(float f) {
    unsigned u = __builtin_bit_cast(unsigned, f);
    u += 0x7FFFu + ((u >> 16) & 1u);          // RNE
    return (unsigned short)(u >> 16);
}
__device__ __forceinline__ float bf2f(unsigned short h) {
    return __builtin_bit_cast(float, (unsigned)h << 16);
}
// tanh(x) = 1 - 2/(1 + 2^(x*2*log2(e))) : 5 VALU ops, exact at +/-inf
__device__ __forceinline__ float tanh5(float x) {
    float z = __builtin_amdgcn_exp2f(x * 2.885390081777927f);
    return __builtin_fmaf(-2.0f, __builtin_amdgcn_rcpf(1.0f + z), 1.0f);
}

// ---- prep: chunked fragment-order weights (verified R6/R7).
// Chunk fc<48: (layer=fc>>4, ch=fc&15): dst[kg*128 + j*8 + kk] = Wmid[layer][8kg+kk][ch*16+j],
//   kg in [0,64). Chunk 48: Wsl, kg in [0,32), rest zero.
__global__ void prep_w(const float* __restrict__ Wmid, const float* __restrict__ Wsl,
                       unsigned short* __restrict__ wtc) {
    const int b = blockIdx.x;       // 0..48
    const int t = threadIdx.x;
    unsigned short* dst = wtc + (size_t)b * 8192;
    if (b < 48) {
        const int layer = b >> 4, ch = b & 15;
        const float* src = Wmid + (size_t)layer * (2 * HD * HD);
#pragma unroll 4
        for (int v = 0; v < 32; ++v) {
            int o = t * 32 + v;
            int kk = o & 7, j = (o >> 3) & 15, kg = o >> 7;
            dst[o] = f2bf(src[(8 * kg + kk) * HD + ch * 16 + j]);
        }
    } else {
#pragma unroll 4
        for (int v = 0; v < 32; ++v) {
            int o = t * 32 + v;
            int kk = o & 7, j = (o >> 3) & 15, kg = o >> 7;
            dst[o] = (kg < 32) ? f2bf(Wsl[(8 * kg + kk) * NI + j]) : (unsigned short)0;
        }
    }
}

struct __align__(16) SMem {
    unsigned short wt[2][4096];           // 16384 B: double-buffered h-part W (kg<32)
    union {
        unsigned short h[BB * NI * ASH];  // 33792 B: bf16 h (in-place across layers)
        float slf[BB][NI * ASH / 2];      // per-element slater scratch (own region)
    } u;
    unsigned short gm[BB * HD];           // 2048 B: bf16 column means per element
    union {
        unsigned short gv[BB * HD];       // 2048 B: bf16 gvec (mid layers)
        struct { float x0[BB * NI]; float gmean[BB]; } x;  // input phase only
    } v;
};
static_assert(sizeof(SMem) == 54272, "LDS budget: 3 blocks/CU needs <= 54613 B");

__device__ __forceinline__ void stage_half(const unsigned short* __restrict__ wtc,
                                           unsigned short* dst_base, int fc, int tid) {
    const unsigned short* gsrc = wtc + (size_t)fc * 8192 + tid * 8;
    __builtin_amdgcn_global_load_lds((as1p)gsrc,          (as3p)(dst_base + tid * 8),        16, 0, 0);
    __builtin_amdgcn_global_load_lds((as1p)(gsrc + 2048), (as3p)(dst_base + tid * 8 + 2048), 16, 0, 0);
}

__global__ __launch_bounds__(256, 3)
void eqslater_mfma(const float* __restrict__ x0g,
                   const float* __restrict__ Win,
                   const float* __restrict__ bin,
                   const float* __restrict__ bmid,
                   const float* __restrict__ bsl,
                   const float* __restrict__ width,
                   const unsigned short* __restrict__ wtc,
                   float* __restrict__ out) {
    __shared__ SMem sm;
    const int tid = threadIdx.x;
    const int bbase = blockIdx.x * BB;
    const int e = tid >> 6;   // wave = element
    const int l = tid & 63;
    const int c = l & 15;     // A-row / B-col / C-col
    const int g = l >> 4;     // k-group

    // ---- stage chunk 0 h-part early: latency hides under the input layer
    stage_half(wtc, sm.wt[0], 0, tid);

    if (tid < BB * NI) sm.v.x.x0[tid] = x0g[bbase * NI + tid];
    __syncthreads();
    if (tid < BB) {
        float s = 0.f;
#pragma unroll
        for (int n = 0; n < NI; ++n) s += sm.v.x.x0[tid * NI + n];
        sm.v.x.gmean[tid] = s * 0.0625f;
    }
    __syncthreads();

    // ---- input layer (fp32 VALU): h = tanh(x0*W0 + g*W1 + b), stored bf16
    {
        const int j = tid;
        const float w0 = Win[j], w1 = Win[HD + j], bj = bin[j];
#pragma unroll 4
        for (int r = 0; r < BB * NI; ++r) {
            float pre = fmaf(sm.v.x.x0[r], w0, fmaf(sm.v.x.gmean[r >> 4], w1, bj));
            sm.u.h[r * ASH + j] = f2bf(tanh5(pre));
        }
    }
    __syncthreads();   // h visible; x0/gmean dead; wt[0] staged (vmcnt drained)

    bf16x8 af[8], agm[8], bq2[8];

#pragma unroll 1
    for (int layer = 0; layer < NMID; ++layer) {
        // ---- gm: column means of own h (wave-private write)
        {
            const int c0 = l * 4;
            float s0 = 0, s1 = 0, s2 = 0, s3 = 0;
#pragma unroll
            for (int r = 0; r < NI; ++r) {
                short4 vq = *(const short4*)&sm.u.h[(e * NI + r) * ASH + c0];
                s0 += bf2f((unsigned short)vq.x);
                s1 += bf2f((unsigned short)vq.y);
                s2 += bf2f((unsigned short)vq.z);
                s3 += bf2f((unsigned short)vq.w);
            }
            short4 o;
            o.x = (short)f2bf(s0 * 0.0625f); o.y = (short)f2bf(s1 * 0.0625f);
            o.z = (short)f2bf(s2 * 0.0625f); o.w = (short)f2bf(s3 * 0.0625f);
            *(short4*)&sm.gm[e * HD + c0] = o;
        }
        // ---- A fragments: own h rows, held in regs across all chunks
#pragma unroll
        for (int s = 0; s < 8; ++s)
            af[s] = *(const bf16x8*)&sm.u.h[(e * NI + c) * ASH + 32 * s + 8 * g];
        __syncthreads();   // gm of ALL elements visible
        // ---- replicated-gm A frags (A row r = gm of element r&3)
#pragma unroll
        for (int s = 0; s < 8; ++s)
            agm[s] = *(const bf16x8*)&sm.gm[(c & 3) * HD + 32 * s + 8 * g];

        const float* bml = bmid + layer * HD;
        f32x4 avp = {0.f, 0.f, 0.f, 0.f};
        float biasp = 0.f;

#pragma unroll 1
        for (int ch = 0; ch < 16; ++ch) {
            const int fc = layer * 16 + ch;
            // (1) issue DMA for next chunk's h-part into the other buffer
            stage_half(wtc, sm.wt[(fc + 1) & 1], fc + 1, tid);
            // (2) owner wave: gm-part B frags straight from global (L2-hot)
            const bool own = (ch >> 2) == e;
            if (own) {
                const unsigned short* gp = wtc + (size_t)fc * 8192 + c * 8 + g * 128;
#pragma unroll
                for (int t2 = 0; t2 < 8; ++t2)
                    bq2[t2] = *(const bf16x8*)(gp + (32 + 4 * t2) * 128);
            }
            const float biasc = bml[ch * 16 + c];

            // (3) h-part GEMM: 8 MFMA from current buffer
            const unsigned short* wb = sm.wt[fc & 1];
            f32x4 p0 = {0.f,0.f,0.f,0.f}, p1 = {0.f,0.f,0.f,0.f};
#pragma unroll
            for (int s = 0; s < 4; ++s) {
                bf16x8 b0 = *(const bf16x8*)&wb[(8 * s     + g) * 128 + c * 8];
                bf16x8 b1 = *(const bf16x8*)&wb[(8 * s + 4 + g) * 128 + c * 8];
                p0 = __builtin_amdgcn_mfma_f32_16x16x32_bf16(af[2 * s],     b0, p0, 0, 0, 0);
                p1 = __builtin_amdgcn_mfma_f32_16x16x32_bf16(af[2 * s + 1], b1, p1, 0, 0, 0);
            }
            f32x4 avc = p0 + p1;

            // (4) rank-1 gm-GEMM: owner computes gvec for ALL 4 elements
            if (own) {
                f32x4 q0 = {0.f,0.f,0.f,0.f}, q1 = {0.f,0.f,0.f,0.f};
#pragma unroll
                for (int s = 0; s < 4; ++s) {
                    q0 = __builtin_amdgcn_mfma_f32_16x16x32_bf16(agm[2 * s],     bq2[2 * s],     q0, 0, 0, 0);
                    q1 = __builtin_amdgcn_mfma_f32_16x16x32_bf16(agm[2 * s + 1], bq2[2 * s + 1], q1, 0, 0, 0);
                }
                f32x4 gq = q0 + q1;   // reg q == gvec[el=q][16ch+c]
                float wv = (g == 0) ? gq[0] : (g == 1) ? gq[1] : (g == 2) ? gq[2] : gq[3];
                sm.v.gv[g * HD + ch * 16 + c] = f2bf(wv);
            }

            // (5) lagged epilogue for chunk ch-1 (gvec(ch-1) barrier-ordered)
            if (ch > 0) {
                const int j = (ch - 1) * 16 + c;
                const float gvv = bf2f(sm.v.gv[e * HD + j]);
#pragma unroll
                for (int q = 0; q < 4; ++q) {
                    const int hidx = (e * NI + 4 * g + q) * ASH + j;
                    float o = tanh5(avp[q] + gvv + biasp) + bf2f(sm.u.h[hidx]);
                    sm.u.h[hidx] = f2bf(o);
                }
            }
            avp = avc; biasp = biasc;
            __syncthreads();   // drains DMA (next buf ready), orders gv/wt reads
        }
        {   // final epilogue of the layer (gvec(15) ordered by last barrier)
            const int j = 15 * 16 + c;
            const float gvv = bf2f(sm.v.gv[e * HD + j]);
#pragma unroll
            for (int q = 0; q < 4; ++q) {
                const int hidx = (e * NI + 4 * g + q) * ASH + j;
                float o = tanh5(avp[q] + gvv + biasp) + bf2f(sm.u.h[hidx]);
                sm.u.h[hidx] = f2bf(o);
            }
        }
    }

    // ---- slater head: wt[0] holds chunk 48 (staged during last mid chunk)
#pragma unroll
    for (int s = 0; s < 8; ++s)
        af[s] = *(const bf16x8*)&sm.u.h[(e * NI + c) * ASH + 32 * s + 8 * g];
    {
        const unsigned short* wb = sm.wt[0];
        f32x4 a0 = {0.f,0.f,0.f,0.f}, a1 = {0.f,0.f,0.f,0.f};
#pragma unroll
        for (int s = 0; s < 4; ++s) {
            bf16x8 b0 = *(const bf16x8*)&wb[(8 * s     + g) * 128 + c * 8];
            bf16x8 b1 = *(const bf16x8*)&wb[(8 * s + 4 + g) * 128 + c * 8];
            a0 = __builtin_amdgcn_mfma_f32_16x16x32_bf16(af[2 * s],     b0, a0, 0, 0, 0);
            a1 = __builtin_amdgcn_mfma_f32_16x16x32_bf16(af[2 * s + 1], b1, a1, 0, 0, 0);
        }
        f32x4 sv = a0 + a1;
        const float bs = bsl[c];
        float* slp = &sm.u.slf[e][0];   // own-element region; own h now dead
#pragma unroll
        for (int q = 0; q < 4; ++q)
            slp[(4 * g + q) * SLS + c] = sv[q] + bs;
    }

    // ---- per-wave slogdet: register LU w/ partial pivoting (R4-verified)
    {
        const float* slp = &sm.u.slf[e][0];
        const int i = c;   // row, 4x duplicated across lanes
        float M[16];
#pragma unroll
        for (int jj = 0; jj < 4; ++jj) {
            float4 vv = *(const float4*)&slp[i * SLS + 4 * jj];
            M[4 * jj] = vv.x; M[4 * jj + 1] = vv.y; M[4 * jj + 2] = vv.z; M[4 * jj + 3] = vv.w;
        }

        float dsign = 1.f, logabs = 0.f;
#pragma unroll
        for (int k = 0; k < 16; ++k) {
            float myv = (i >= k) ? __builtin_fabsf(M[k]) : -1.f;
            float maxv = myv;
#pragma unroll
            for (int off = 32; off > 0; off >>= 1)
                maxv = fmaxf(maxv, __shfl_xor(maxv, off));
            unsigned long long bal = __ballot(myv == maxv);
            int p = (__ffsll((long long)bal) - 1) & 15;

            if (p != k) {
                dsign = -dsign;
#pragma unroll
                for (int j = 0; j < 16; ++j) {
                    float vk = __shfl(M[j], k);
                    float vp = __shfl(M[j], p);
                    if (i == k) M[j] = vp;
                    if (i == p) M[j] = vk;
                }
            }
            float piv = __shfl(M[k], k);
            // NaN guard (singular matrix): finite logabs, no 0/0 poison.
            float ap = fmaxf(__builtin_fabsf(piv), 1e-35f);
            logabs += __logf(ap);
            if (piv < 0.f) dsign = -dsign;
            float spiv = __builtin_copysignf(ap, piv);
            float mi = __fdividef(M[k], spiv);
#pragma unroll
            for (int j = k + 1; j < 16; ++j) {
                float vkj = __shfl(M[j], k);
                if (i > k) M[j] = __builtin_fmaf(-mi, vkj, M[j]);
            }
        }

        float xv = (l < NI) ? x0g[(bbase + e) * NI + l] : 0.f;
        float sq = xv * xv;
#pragma unroll
        for (int off = 8; off > 0; off >>= 1) sq += __shfl_xor(sq, off);

        if (l == 0) {
            out[bbase + e] = dsign;
            out[BTOT + bbase + e] = logabs - HALF_LOGFACT - width[0] * sq;
        }
    }
}

extern "C" void kernel_launch(void* const* d_in, const int* in_sizes, int n_in,
                              void* d_out, int out_size, void* d_ws, size_t ws_size,
                              hipStream_t stream) {
    const float* x0   = (const float*)d_in[0];
    const float* Win  = (const float*)d_in[1];
    const float* bin  = (const float*)d_in[2];
    const float* Wmid = (const float*)d_in[3];
    const float* bmid = (const float*)d_in[4];
    const float* Wsl  = (const float*)d_in[5];
    const float* bsl  = (const float*)d_in[6];
    const float* wid  = (const float*)d_in[7];
    float* out = (float*)d_out;

    unsigned short* wtc = (unsigned short*)d_ws;   // 49 * 16384 B = 802816 B

    hipLaunchKernelGGL(prep_w, dim3(49), dim3(256), 0, stream, Wmid, Wsl, wtc);
    hipLaunchKernelGGL(eqslater_mfma, dim3(BTOT / BB), dim3(256), 0, stream,
                       x0, Win, bin, bmid, bsl, wid, wtc, out);
}

// Round 9
// 440.705 us; speedup vs baseline: 1.1888x; 1.0825x over previous
//
#include <hip/hip_runtime.h>

// Problem constants
#define BTOT 16384
#define NI   16
#define HD   256
#define BB   4            // elements per block = waves per block
#define NMID 3
#define ASH  264          // h LDS row stride in bf16 (528B, 16B-aligned)
#define SLS  20           // slater scratch row stride (floats)
#define HALF_LOGFACT 15.3359295387f  // 0.5 * ln(16!)

typedef short  bf16x8 __attribute__((ext_vector_type(8)));
typedef float  f32x4  __attribute__((ext_vector_type(4)));
typedef const __attribute__((address_space(1))) unsigned int* as1p;
typedef __attribute__((address_space(3))) unsigned int* as3p;

__device__ __forceinline__ unsigned short f2bf(float f) {
    unsigned u = __builtin_bit_cast(unsigned, f);
    u += 0x7FFFu + ((u >> 16) & 1u);          // RNE
    return (unsigned short)(u >> 16);
}
__device__ __forceinline__ float bf2f(unsigned short h) {
    return __builtin_bit_cast(float, (unsigned)h << 16);
}
// tanh(x) = 1 - 2/(1 + 2^(x*2*log2(e))) : 5 VALU ops
__device__ __forceinline__ float tanh5(float x) {
    float z = __builtin_amdgcn_exp2f(x * 2.885390081777927f);
    return __builtin_fmaf(-2.0f, __builtin_amdgcn_rcpf(1.0f + z), 1.0f);
}

// ---- prep: chunked fragment-order weights (verified R6-R8).
// Chunk fc<48: (layer=fc>>4, ch=fc&15): dst[kg*128 + j*8 + kk] = Wmid[layer][8kg+kk][ch*16+j],
//   kg in [0,64). Chunk 48: Wsl, kg in [0,32), rest zero.
__global__ void prep_w(const float* __restrict__ Wmid, const float* __restrict__ Wsl,
                       unsigned short* __restrict__ wtc) {
    const int b = blockIdx.x;       // 0..48
    const int t = threadIdx.x;
    unsigned short* dst = wtc + (size_t)b * 8192;
    if (b < 48) {
        const int layer = b >> 4, ch = b & 15;
        const float* src = Wmid + (size_t)layer * (2 * HD * HD);
#pragma unroll 4
        for (int v = 0; v < 32; ++v) {
            int o = t * 32 + v;
            int kk = o & 7, j = (o >> 3) & 15, kg = o >> 7;
            dst[o] = f2bf(src[(8 * kg + kk) * HD + ch * 16 + j]);
        }
    } else {
#pragma unroll 4
        for (int v = 0; v < 32; ++v) {
            int o = t * 32 + v;
            int kk = o & 7, j = (o >> 3) & 15, kg = o >> 7;
            dst[o] = (kg < 32) ? f2bf(Wsl[(8 * kg + kk) * NI + j]) : (unsigned short)0;
        }
    }
}

struct __align__(16) SMem {
    unsigned short wt[3][4096];           // 24576 B: 3-deep ring of h-part W (kg<32)
    union {
        unsigned short h[BB * NI * ASH];  // 33792 B: bf16 h (in-place across layers)
        float slf[BB][NI * ASH / 2];      // per-element slater scratch (own region)
    } u;
    unsigned short gm[BB * HD];           // 2048 B
    union {
        unsigned short gv[BB * HD];       // 2048 B: bf16 gvec (mid layers)
        struct { float x0[BB * NI]; float gmean[BB]; } x;  // input phase only
    } v;
};
static_assert(sizeof(SMem) <= 62464, "LDS: 2 blocks/CU");

__device__ __forceinline__ void stage_half(const unsigned short* __restrict__ wtc,
                                           unsigned short* dst_base, int fc, int tid) {
    const unsigned short* gsrc = wtc + (size_t)fc * 8192 + tid * 8;
    __builtin_amdgcn_global_load_lds((as1p)gsrc,          (as3p)(dst_base + tid * 8),        16, 0, 0);
    __builtin_amdgcn_global_load_lds((as1p)(gsrc + 2048), (as3p)(dst_base + tid * 8 + 2048), 16, 0, 0);
}

__global__ __launch_bounds__(256, 2)
void eqslater_mfma(const float* __restrict__ x0g,
                   const float* __restrict__ Win,
                   const float* __restrict__ bin,
                   const float* __restrict__ bmid,
                   const float* __restrict__ bsl,
                   const float* __restrict__ width,
                   const unsigned short* __restrict__ wtc,
                   float* __restrict__ out) {
    __shared__ SMem sm;
    const int tid = threadIdx.x;
    const int bbase = blockIdx.x * BB;
    const int e = tid >> 6;   // wave = element
    const int l = tid & 63;
    const int c = l & 15;     // A-row / B-col / C-col
    const int g = l >> 4;     // k-group

    // ---- prologue: stage chunks 0,1 (latency hidden by input layer)
    stage_half(wtc, sm.wt[0], 0, tid);
    stage_half(wtc, sm.wt[1], 1, tid);

    if (tid < BB * NI) sm.v.x.x0[tid] = x0g[bbase * NI + tid];
    __syncthreads();
    if (tid < BB) {
        float s = 0.f;
#pragma unroll
        for (int n = 0; n < NI; ++n) s += sm.v.x.x0[tid * NI + n];
        sm.v.x.gmean[tid] = s * 0.0625f;
    }
    __syncthreads();

    // ---- input layer (fp32 VALU): h = tanh(x0*W0 + g*W1 + b), stored bf16
    {
        const int j = tid;
        const float w0 = Win[j], w1 = Win[HD + j], bj = bin[j];
#pragma unroll 4
        for (int r = 0; r < BB * NI; ++r) {
            float pre = fmaf(sm.v.x.x0[r], w0, fmaf(sm.v.x.gmean[r >> 4], w1, bj));
            sm.u.h[r * ASH + j] = f2bf(tanh5(pre));
        }
    }
    __syncthreads();   // ONE full drain: h visible, wt[0..1] staged, x0 dead

    bf16x8 af[8], agm[8], bq2[8];

#pragma unroll 1
    for (int layer = 0; layer < NMID; ++layer) {
        // ---- gm: column means of own h (wave-private; after own final epilogue)
        {
            const int c0 = l * 4;
            float s0 = 0, s1 = 0, s2 = 0, s3 = 0;
#pragma unroll
            for (int r = 0; r < NI; ++r) {
                short4 vq = *(const short4*)&sm.u.h[(e * NI + r) * ASH + c0];
                s0 += bf2f((unsigned short)vq.x);
                s1 += bf2f((unsigned short)vq.y);
                s2 += bf2f((unsigned short)vq.z);
                s3 += bf2f((unsigned short)vq.w);
            }
            short4 o;
            o.x = (short)f2bf(s0 * 0.0625f); o.y = (short)f2bf(s1 * 0.0625f);
            o.z = (short)f2bf(s2 * 0.0625f); o.w = (short)f2bf(s3 * 0.0625f);
            *(short4*)&sm.gm[e * HD + c0] = o;
        }
#pragma unroll
        for (int s = 0; s < 8; ++s)
            af[s] = *(const bf16x8*)&sm.u.h[(e * NI + c) * ASH + 32 * s + 8 * g];
        // gm visible to all (NO vmcnt drain: staging stays in flight)
        asm volatile("s_waitcnt lgkmcnt(0)" ::: "memory");
        __builtin_amdgcn_s_barrier();
        __builtin_amdgcn_sched_barrier(0);
#pragma unroll
        for (int s = 0; s < 8; ++s)
            agm[s] = *(const bf16x8*)&sm.gm[(c & 3) * HD + 32 * s + 8 * g];

        const float* bml = bmid + layer * HD;
        f32x4 avp = {0.f, 0.f, 0.f, 0.f};
        float biasp = 0.f;

#pragma unroll 1
        for (int ch = 0; ch < 16; ++ch) {
            const int fc = layer * 16 + ch;
            // counted wait: chunk fc ready, fc+1 stays IN FLIGHT (never vmcnt(0))
            asm volatile("s_waitcnt vmcnt(2) lgkmcnt(0)" ::: "memory");
            __builtin_amdgcn_s_barrier();
            __builtin_amdgcn_sched_barrier(0);

            const bool own = (ch >> 2) == e;
            if (own) {   // gm-part B frags from global, issued BEFORE stage ->
                         // their auto-wait is vmcnt(2), not a queue drain
                const unsigned short* gp = wtc + (size_t)fc * 8192 + c * 8 + g * 128;
#pragma unroll
                for (int t2 = 0; t2 < 8; ++t2)
                    bq2[t2] = *(const bf16x8*)(gp + (32 + 4 * t2) * 128);
            }
            __builtin_amdgcn_sched_barrier(0);
            if (fc + 2 <= 48) stage_half(wtc, sm.wt[(fc + 2) % 3], fc + 2, tid);
            __builtin_amdgcn_sched_barrier(0);

            const float biasc = bml[ch * 16 + c];
            // lagged epilogue ch-1 (covers bq2 + ds_read latency)
            if (ch > 0) {
                const int j = (ch - 1) * 16 + c;
                const float gvv = bf2f(sm.v.gv[e * HD + j]);
#pragma unroll
                for (int q = 0; q < 4; ++q) {
                    const int hidx = (e * NI + 4 * g + q) * ASH + j;
                    float o = tanh5(avp[q] + gvv + biasp) + bf2f(sm.u.h[hidx]);
                    sm.u.h[hidx] = f2bf(o);
                }
            }

            // h-part GEMM: 8 MFMA from ring buffer fc%3
            const unsigned short* wb = sm.wt[fc % 3];
            f32x4 p0 = {0.f,0.f,0.f,0.f}, p1 = {0.f,0.f,0.f,0.f};
#pragma unroll
            for (int s = 0; s < 4; ++s) {
                bf16x8 b0 = *(const bf16x8*)&wb[(8 * s     + g) * 128 + c * 8];
                bf16x8 b1 = *(const bf16x8*)&wb[(8 * s + 4 + g) * 128 + c * 8];
                p0 = __builtin_amdgcn_mfma_f32_16x16x32_bf16(af[2 * s],     b0, p0, 0, 0, 0);
                p1 = __builtin_amdgcn_mfma_f32_16x16x32_bf16(af[2 * s + 1], b1, p1, 0, 0, 0);
            }
            f32x4 avc = p0 + p1;

            // rank-1 gm-GEMM: owner computes gvec for ALL 4 elements
            if (own) {
                f32x4 q0 = {0.f,0.f,0.f,0.f}, q1 = {0.f,0.f,0.f,0.f};
#pragma unroll
                for (int s = 0; s < 4; ++s) {
                    q0 = __builtin_amdgcn_mfma_f32_16x16x32_bf16(agm[2 * s],     bq2[2 * s],     q0, 0, 0, 0);
                    q1 = __builtin_amdgcn_mfma_f32_16x16x32_bf16(agm[2 * s + 1], bq2[2 * s + 1], q1, 0, 0, 0);
                }
                f32x4 gq = q0 + q1;   // row 4g+g -> element g's gvec value
                float wv = (g == 0) ? gq[0] : (g == 1) ? gq[1] : (g == 2) ? gq[2] : gq[3];
                sm.v.gv[g * HD + ch * 16 + c] = f2bf(wv);
            }
            avp = avc; biasp = biasc;
        }
        // layer end: gv(15) visible (lgkm only; DMA for next layer stays in flight)
        asm volatile("s_waitcnt lgkmcnt(0)" ::: "memory");
        __builtin_amdgcn_s_barrier();
        __builtin_amdgcn_sched_barrier(0);
        {   // final epilogue of the layer
            const int j = 15 * 16 + c;
            const float gvv = bf2f(sm.v.gv[e * HD + j]);
#pragma unroll
            for (int q = 0; q < 4; ++q) {
                const int hidx = (e * NI + 4 * g + q) * ASH + j;
                float o = tanh5(avp[q] + gvv + biasp) + bf2f(sm.u.h[hidx]);
                sm.u.h[hidx] = f2bf(o);
            }
        }
    }

    // ---- slater head: chunk 48 in wt[0] (48%3==0)
#pragma unroll
    for (int s = 0; s < 8; ++s)
        af[s] = *(const bf16x8*)&sm.u.h[(e * NI + c) * ASH + 32 * s + 8 * g];
    asm volatile("s_waitcnt vmcnt(0) lgkmcnt(0)" ::: "memory");
    __builtin_amdgcn_s_barrier();
    __builtin_amdgcn_sched_barrier(0);
    {
        const unsigned short* wb = sm.wt[0];
        f32x4 a0 = {0.f,0.f,0.f,0.f}, a1 = {0.f,0.f,0.f,0.f};
#pragma unroll
        for (int s = 0; s < 4; ++s) {
            bf16x8 b0 = *(const bf16x8*)&wb[(8 * s     + g) * 128 + c * 8];
            bf16x8 b1 = *(const bf16x8*)&wb[(8 * s + 4 + g) * 128 + c * 8];
            a0 = __builtin_amdgcn_mfma_f32_16x16x32_bf16(af[2 * s],     b0, a0, 0, 0, 0);
            a1 = __builtin_amdgcn_mfma_f32_16x16x32_bf16(af[2 * s + 1], b1, a1, 0, 0, 0);
        }
        f32x4 sv = a0 + a1;
        const float bs = bsl[c];
        float* slp = &sm.u.slf[e][0];   // own-element region; own h now dead
#pragma unroll
        for (int q = 0; q < 4; ++q)
            slp[(4 * g + q) * SLS + c] = sv[q] + bs;
    }

    // ---- per-wave slogdet: register LU w/ partial pivoting (R4-verified)
    {
        const float* slp = &sm.u.slf[e][0];
        const int i = c;   // row, 4x duplicated across lanes
        float M[16];
#pragma unroll
        for (int jj = 0; jj < 4; ++jj) {
            float4 vv = *(const float4*)&slp[i * SLS + 4 * jj];
            M[4 * jj] = vv.x; M[4 * jj + 1] = vv.y; M[4 * jj + 2] = vv.z; M[4 * jj + 3] = vv.w;
        }

        float dsign = 1.f, logabs = 0.f;
#pragma unroll
        for (int k = 0; k < 16; ++k) {
            float myv = (i >= k) ? __builtin_fabsf(M[k]) : -1.f;
            float maxv = myv;
#pragma unroll
            for (int off = 32; off > 0; off >>= 1)
                maxv = fmaxf(maxv, __shfl_xor(maxv, off));
            unsigned long long bal = __ballot(myv == maxv);
            int p = (__ffsll((long long)bal) - 1) & 15;

            if (p != k) {
                dsign = -dsign;
#pragma unroll
                for (int j = 0; j < 16; ++j) {
                    float vk = __shfl(M[j], k);
                    float vp = __shfl(M[j], p);
                    if (i == k) M[j] = vp;
                    if (i == p) M[j] = vk;
                }
            }
            float piv = __shfl(M[k], k);
            // NaN guard (singular matrix): finite logabs, no 0/0 poison.
            float ap = fmaxf(__builtin_fabsf(piv), 1e-35f);
            logabs += __logf(ap);
            if (piv < 0.f) dsign = -dsign;
            float spiv = __builtin_copysignf(ap, piv);
            float mi = __fdividef(M[k], spiv);
#pragma unroll
            for (int j = k + 1; j < 16; ++j) {
                float vkj = __shfl(M[j], k);
                if (i > k) M[j] = __builtin_fmaf(-mi, vkj, M[j]);
            }
        }

        float xv = (l < NI) ? x0g[(bbase + e) * NI + l] : 0.f;
        float sq = xv * xv;
#pragma unroll
        for (int off = 8; off > 0; off >>= 1) sq += __shfl_xor(sq, off);

        if (l == 0) {
            out[bbase + e] = dsign;
            out[BTOT + bbase + e] = logabs - HALF_LOGFACT - width[0] * sq;
        }
    }
}

extern "C" void kernel_launch(void* const* d_in, const int* in_sizes, int n_in,
                              void* d_out, int out_size, void* d_ws, size_t ws_size,
                              hipStream_t stream) {
    const float* x0   = (const float*)d_in[0];
    const float* Win  = (const float*)d_in[1];
    const float* bin  = (const float*)d_in[2];
    const float* Wmid = (const float*)d_in[3];
    const float* bmid = (const float*)d_in[4];
    const float* Wsl  = (const float*)d_in[5];
    const float* bsl  = (const float*)d_in[6];
    const float* wid  = (const float*)d_in[7];
    float* out = (float*)d_out;

    unsigned short* wtc = (unsigned short*)d_ws;   // 49 * 16384 B = 802816 B

    hipLaunchKernelGGL(prep_w, dim3(49), dim3(256), 0, stream, Wmid, Wsl, wtc);
    hipLaunchKernelGGL(eqslater_mfma, dim3(BTOT / BB), dim3(256), 0, stream,
                       x0, Win, bin, bmid, bsl, wid, wtc, out);
}

// Round 10
// 397.922 us; speedup vs baseline: 1.3167x; 1.1075x over previous
//
#include <hip/hip_runtime.h>

// Problem constants
#define BTOT 16384
#define NI   16
#define HD   256
#define BB   4            // elements per block = waves per block
#define NMID 3
#define ASH  264          // h LDS row stride in bf16 (528B, 16B-aligned)
#define SLS  20           // slater scratch row stride (floats)
#define HALF_LOGFACT 15.3359295387f  // 0.5 * ln(16!)

typedef short  bf16x8 __attribute__((ext_vector_type(8)));
typedef float  f32x4  __attribute__((ext_vector_type(4)));
typedef const __attribute__((address_space(1))) unsigned int* as1p;
typedef __attribute__((address_space(3))) unsigned int* as3p;

__device__ __forceinline__ unsigned short f2bf(float f) {
    unsigned u = __builtin_bit_cast(unsigned, f);
    u += 0x7FFFu + ((u >> 16) & 1u);          // RNE
    return (unsigned short)(u >> 16);
}
__device__ __forceinline__ float bf2f(unsigned short h) {
    return __builtin_bit_cast(float, (unsigned)h << 16);
}
// tanh(x) = 1 - 2/(1 + 2^(x*2*log2(e))) : 5 VALU ops
__device__ __forceinline__ float tanh5(float x) {
    float z = __builtin_amdgcn_exp2f(x * 2.885390081777927f);
    return __builtin_fmaf(-2.0f, __builtin_amdgcn_rcpf(1.0f + z), 1.0f);
}

// ---- prep: chunked fragment-order weights (verified R6-R9).
// Chunk fc<48: (layer=fc>>4, ch=fc&15): dst[kg*128 + j*8 + kk] = Wmid[layer][8kg+kk][ch*16+j],
//   kg in [0,64). Chunk 48: Wsl, kg in [0,32), rest zero.
__global__ void prep_w(const float* __restrict__ Wmid, const float* __restrict__ Wsl,
                       unsigned short* __restrict__ wtc) {
    const int b = blockIdx.x;       // 0..48
    const int t = threadIdx.x;
    unsigned short* dst = wtc + (size_t)b * 8192;
    if (b < 48) {
        const int layer = b >> 4, ch = b & 15;
        const float* src = Wmid + (size_t)layer * (2 * HD * HD);
#pragma unroll 4
        for (int v = 0; v < 32; ++v) {
            int o = t * 32 + v;
            int kk = o & 7, j = (o >> 3) & 15, kg = o >> 7;
            dst[o] = f2bf(src[(8 * kg + kk) * HD + ch * 16 + j]);
        }
    } else {
#pragma unroll 4
        for (int v = 0; v < 32; ++v) {
            int o = t * 32 + v;
            int kk = o & 7, j = (o >> 3) & 15, kg = o >> 7;
            dst[o] = (kg < 32) ? f2bf(Wsl[(8 * kg + kk) * NI + j]) : (unsigned short)0;
        }
    }
}

struct __align__(16) SMem {
    unsigned short wt[2][4096];           // 16384 B: 2-ring of h-part W (kg<32)
    union {
        unsigned short h[BB * NI * ASH];  // 33792 B: bf16 h (in-place across layers)
        float slf[BB][NI * ASH / 2];      // per-element slater scratch (own region)
    } u;
    union {
        unsigned short gmgv[BB * HD];     // 2048 B: gm at layer top; gv overwrites
                                          // progressively (agm is reg-resident)
        struct { float x0[BB * NI]; float gmean[BB]; } x;  // input phase only
    } v;
};
static_assert(sizeof(SMem) == 52224, "must be < ~52.7KB for 3 blocks/CU (R6 evidence)");

__device__ __forceinline__ void stage_half(const unsigned short* __restrict__ wtc,
                                           unsigned short* dst_base, int fc, int tid) {
    const unsigned short* gsrc = wtc + (size_t)fc * 8192 + tid * 8;
    __builtin_amdgcn_global_load_lds((as1p)gsrc,          (as3p)(dst_base + tid * 8),        16, 0, 0);
    __builtin_amdgcn_global_load_lds((as1p)(gsrc + 2048), (as3p)(dst_base + tid * 8 + 2048), 16, 0, 0);
}

__global__ __launch_bounds__(256, 3)
void eqslater_mfma(const float* __restrict__ x0g,
                   const float* __restrict__ Win,
                   const float* __restrict__ bin,
                   const float* __restrict__ bmid,
                   const float* __restrict__ bsl,
                   const float* __restrict__ width,
                   const unsigned short* __restrict__ wtc,
                   float* __restrict__ out) {
    __shared__ SMem sm;
    const int tid = threadIdx.x;
    const int bbase = blockIdx.x * BB;
    const int e = tid >> 6;   // wave = element
    const int l = tid & 63;
    const int c = l & 15;     // h-row (B-col / C-col in transposed orientation)
    const int g = l >> 4;     // k-group; C rows 4g..4g+3 -> cols j = 16ch+4g+q

    // ---- prologue: stage chunk 0 (latency hidden by input layer)
    stage_half(wtc, sm.wt[0], 0, tid);

    if (tid < BB * NI) sm.v.x.x0[tid] = x0g[bbase * NI + tid];
    __syncthreads();
    if (tid < BB) {
        float s = 0.f;
#pragma unroll
        for (int n = 0; n < NI; ++n) s += sm.v.x.x0[tid * NI + n];
        sm.v.x.gmean[tid] = s * 0.0625f;
    }
    __syncthreads();

    // ---- input layer (fp32 VALU): h = tanh(x0*W0 + g*W1 + b), stored bf16
    {
        const int j = tid;
        const float w0 = Win[j], w1 = Win[HD + j], bj = bin[j];
#pragma unroll 4
        for (int r = 0; r < BB * NI; ++r) {
            float pre = fmaf(sm.v.x.x0[r], w0, fmaf(sm.v.x.gmean[r >> 4], w1, bj));
            sm.u.h[r * ASH + j] = f2bf(tanh5(pre));
        }
    }
    __syncthreads();   // ONE full drain: h visible, wt[0] staged, x dead

    bf16x8 af[8], agm[8], bq2[8];
    const int j4 = 4 * g;     // per-lane column sub-offset

#pragma unroll 1
    for (int layer = 0; layer < NMID; ++layer) {
        // ---- gm: column means of own h -> gmgv[e] (wave-private write)
        {
            const int c0 = l * 4;
            float s0 = 0, s1 = 0, s2 = 0, s3 = 0;
#pragma unroll
            for (int r = 0; r < NI; ++r) {
                short4 vq = *(const short4*)&sm.u.h[(e * NI + r) * ASH + c0];
                s0 += bf2f((unsigned short)vq.x);
                s1 += bf2f((unsigned short)vq.y);
                s2 += bf2f((unsigned short)vq.z);
                s3 += bf2f((unsigned short)vq.w);
            }
            short4 o;
            o.x = (short)f2bf(s0 * 0.0625f); o.y = (short)f2bf(s1 * 0.0625f);
            o.z = (short)f2bf(s2 * 0.0625f); o.w = (short)f2bf(s3 * 0.0625f);
            *(short4*)&sm.v.gmgv[e * HD + c0] = o;
        }
#pragma unroll
        for (int s = 0; s < 8; ++s)
            af[s] = *(const bf16x8*)&sm.u.h[(e * NI + c) * ASH + 32 * s + 8 * g];
        asm volatile("s_waitcnt lgkmcnt(0)" ::: "memory");
        __builtin_amdgcn_s_barrier();
        __builtin_amdgcn_sched_barrier(0);
        // replicated-gm B frags (B col r = gm of element r&3) -> registers
#pragma unroll
        for (int s = 0; s < 8; ++s)
            agm[s] = *(const bf16x8*)&sm.v.gmgv[(c & 3) * HD + 32 * s + 8 * g];

        const float* bml = bmid + layer * HD;
        f32x4 avp = {0.f, 0.f, 0.f, 0.f};
        float4 biasp = {0.f, 0.f, 0.f, 0.f};

#pragma unroll 1
        for (int ch = 0; ch < 16; ++ch) {
            const int fc = layer * 16 + ch;
            // stage(fc) was issued a full chunk ago -> this drain is cheap
            asm volatile("s_waitcnt vmcnt(0) lgkmcnt(0)" ::: "memory");
            __builtin_amdgcn_s_barrier();
            __builtin_amdgcn_sched_barrier(0);

            const bool own = (ch >> 2) == e;
            if (own) {   // gm-part W frags from global (L2-hot), issued first
                const unsigned short* gp = wtc + (size_t)fc * 8192 + c * 8 + g * 128;
#pragma unroll
                for (int t2 = 0; t2 < 8; ++t2)
                    bq2[t2] = *(const bf16x8*)(gp + (32 + 4 * t2) * 128);
            }
            __builtin_amdgcn_sched_barrier(0);
            if (fc < 48) stage_half(wtc, sm.wt[(fc + 1) & 1], fc + 1, tid);
            __builtin_amdgcn_sched_barrier(0);

            const float4 biasc = *(const float4*)&bml[ch * 16 + j4];
            // lagged epilogue ch-1: vectorized (b64 read/modify/write of own row c)
            if (ch > 0) {
                const int jp = (ch - 1) * 16 + j4;
                unsigned short* hrow = &sm.u.h[(e * NI + c) * ASH + jp];
                const ushort4 gvq = *(const ushort4*)&sm.v.gmgv[e * HD + jp];
                const ushort4 res = *(const ushort4*)hrow;
                ushort4 w;
                w.x = f2bf(tanh5(avp[0] + bf2f(gvq.x) + biasp.x) + bf2f(res.x));
                w.y = f2bf(tanh5(avp[1] + bf2f(gvq.y) + biasp.y) + bf2f(res.y));
                w.z = f2bf(tanh5(avp[2] + bf2f(gvq.z) + biasp.z) + bf2f(res.z));
                w.w = f2bf(tanh5(avp[3] + bf2f(gvq.w) + biasp.w) + bf2f(res.w));
                *(ushort4*)hrow = w;
            }

            // h-part GEMM (transposed: A=W frag, B=h frag) -> C[j=16ch+4g+q][r=c]
            const unsigned short* wb = sm.wt[fc & 1];
            f32x4 p0 = {0.f,0.f,0.f,0.f}, p1 = {0.f,0.f,0.f,0.f};
#pragma unroll
            for (int s = 0; s < 4; ++s) {
                bf16x8 b0 = *(const bf16x8*)&wb[(8 * s     + g) * 128 + c * 8];
                bf16x8 b1 = *(const bf16x8*)&wb[(8 * s + 4 + g) * 128 + c * 8];
                p0 = __builtin_amdgcn_mfma_f32_16x16x32_bf16(b0, af[2 * s],     p0, 0, 0, 0);
                p1 = __builtin_amdgcn_mfma_f32_16x16x32_bf16(b1, af[2 * s + 1], p1, 0, 0, 0);
            }
            f32x4 avc = p0 + p1;

            // rank-1 gm-GEMM: owner computes gvec for ALL 4 elements
            if (own) {
                f32x4 q0 = {0.f,0.f,0.f,0.f}, q1 = {0.f,0.f,0.f,0.f};
#pragma unroll
                for (int s = 0; s < 4; ++s) {
                    q0 = __builtin_amdgcn_mfma_f32_16x16x32_bf16(bq2[2 * s],     agm[2 * s],     q0, 0, 0, 0);
                    q1 = __builtin_amdgcn_mfma_f32_16x16x32_bf16(bq2[2 * s + 1], agm[2 * s + 1], q1, 0, 0, 0);
                }
                f32x4 gq = q0 + q1;   // lane (g,c): gvec[el=c&3][j=16ch+4g+q]
                if (c < 4) {
                    ushort4 w;
                    w.x = f2bf(gq[0]); w.y = f2bf(gq[1]);
                    w.z = f2bf(gq[2]); w.w = f2bf(gq[3]);
                    *(ushort4*)&sm.v.gmgv[c * HD + ch * 16 + j4] = w;
                }
            }
            avp = avc; biasp = biasc;
        }
        // layer end: gv(15) visible (lgkm only; DMA stays in flight)
        asm volatile("s_waitcnt lgkmcnt(0)" ::: "memory");
        __builtin_amdgcn_s_barrier();
        __builtin_amdgcn_sched_barrier(0);
        {   // final epilogue of the layer
            const int jp = 240 + j4;
            unsigned short* hrow = &sm.u.h[(e * NI + c) * ASH + jp];
            const ushort4 gvq = *(const ushort4*)&sm.v.gmgv[e * HD + jp];
            const ushort4 res = *(const ushort4*)hrow;
            ushort4 w;
            w.x = f2bf(tanh5(avp[0] + bf2f(gvq.x) + biasp.x) + bf2f(res.x));
            w.y = f2bf(tanh5(avp[1] + bf2f(gvq.y) + biasp.y) + bf2f(res.y));
            w.z = f2bf(tanh5(avp[2] + bf2f(gvq.z) + biasp.z) + bf2f(res.z));
            w.w = f2bf(tanh5(avp[3] + bf2f(gvq.w) + biasp.w) + bf2f(res.w));
            *(ushort4*)hrow = w;
        }
        __builtin_amdgcn_sched_barrier(0);   // keep epilogue DS ops before next gm pass
    }

    // ---- slater head: chunk 48 in wt[0] (48&1==0)
#pragma unroll
    for (int s = 0; s < 8; ++s)
        af[s] = *(const bf16x8*)&sm.u.h[(e * NI + c) * ASH + 32 * s + 8 * g];
    asm volatile("s_waitcnt vmcnt(0) lgkmcnt(0)" ::: "memory");
    __builtin_amdgcn_s_barrier();
    __builtin_amdgcn_sched_barrier(0);
    {
        const unsigned short* wb = sm.wt[0];
        f32x4 a0 = {0.f,0.f,0.f,0.f}, a1 = {0.f,0.f,0.f,0.f};
#pragma unroll
        for (int s = 0; s < 4; ++s) {
            bf16x8 b0 = *(const bf16x8*)&wb[(8 * s     + g) * 128 + c * 8];
            bf16x8 b1 = *(const bf16x8*)&wb[(8 * s + 4 + g) * 128 + c * 8];
            a0 = __builtin_amdgcn_mfma_f32_16x16x32_bf16(b0, af[2 * s],     a0, 0, 0, 0);
            a1 = __builtin_amdgcn_mfma_f32_16x16x32_bf16(b1, af[2 * s + 1], a1, 0, 0, 0);
        }
        f32x4 sv = a0 + a1;   // lane (g,c): sl[row r=c][m=4g+q]
        const float4 bsv = *(const float4*)&bsl[j4];
        float* slp = &sm.u.slf[e][0];   // own-element region; own h now dead
        float4 o;
        o.x = sv[0] + bsv.x; o.y = sv[1] + bsv.y;
        o.z = sv[2] + bsv.z; o.w = sv[3] + bsv.w;
        *(float4*)&slp[c * SLS + j4] = o;
    }

    // ---- per-wave slogdet: register LU w/ partial pivoting (R4-verified)
    {
        const float* slp = &sm.u.slf[e][0];
        const int i = c;   // row, 4x duplicated across lanes
        float M[16];
#pragma unroll
        for (int jj = 0; jj < 4; ++jj) {
            float4 vv = *(const float4*)&slp[i * SLS + 4 * jj];
            M[4 * jj] = vv.x; M[4 * jj + 1] = vv.y; M[4 * jj + 2] = vv.z; M[4 * jj + 3] = vv.w;
        }

        float dsign = 1.f, logabs = 0.f;
#pragma unroll
        for (int k = 0; k < 16; ++k) {
            float myv = (i >= k) ? __builtin_fabsf(M[k]) : -1.f;
            float maxv = myv;
#pragma unroll
            for (int off = 32; off > 0; off >>= 1)
                maxv = fmaxf(maxv, __shfl_xor(maxv, off));
            unsigned long long bal = __ballot(myv == maxv);
            int p = (__ffsll((long long)bal) - 1) & 15;

            if (p != k) {
                dsign = -dsign;
#pragma unroll
                for (int j = 0; j < 16; ++j) {
                    float vk = __shfl(M[j], k);
                    float vp = __shfl(M[j], p);
                    if (i == k) M[j] = vp;
                    if (i == p) M[j] = vk;
                }
            }
            float piv = __shfl(M[k], k);
            // NaN guard (singular matrix): finite logabs, no 0/0 poison.
            float ap = fmaxf(__builtin_fabsf(piv), 1e-35f);
            logabs += __logf(ap);
            if (piv < 0.f) dsign = -dsign;
            float spiv = __builtin_copysignf(ap, piv);
            float mi = __fdividef(M[k], spiv);
#pragma unroll
            for (int j = k + 1; j < 16; ++j) {
                float vkj = __shfl(M[j], k);
                if (i > k) M[j] = __builtin_fmaf(-mi, vkj, M[j]);
            }
        }

        float xv = (l < NI) ? x0g[(bbase + e) * NI + l] : 0.f;
        float sq = xv * xv;
#pragma unroll
        for (int off = 8; off > 0; off >>= 1) sq += __shfl_xor(sq, off);

        if (l == 0) {
            out[bbase + e] = dsign;
            out[BTOT + bbase + e] = logabs - HALF_LOGFACT - width[0] * sq;
        }
    }
}

extern "C" void kernel_launch(void* const* d_in, const int* in_sizes, int n_in,
                              void* d_out, int out_size, void* d_ws, size_t ws_size,
                              hipStream_t stream) {
    const float* x0   = (const float*)d_in[0];
    const float* Win  = (const float*)d_in[1];
    const float* bin  = (const float*)d_in[2];
    const float* Wmid = (const float*)d_in[3];
    const float* bmid = (const float*)d_in[4];
    const float* Wsl  = (const float*)d_in[5];
    const float* bsl  = (const float*)d_in[6];
    const float* wid  = (const float*)d_in[7];
    float* out = (float*)d_out;

    unsigned short* wtc = (unsigned short*)d_ws;   // 49 * 16384 B = 802816 B

    hipLaunchKernelGGL(prep_w, dim3(49), dim3(256), 0, stream, Wmid, Wsl, wtc);
    hipLaunchKernelGGL(eqslater_mfma, dim3(BTOT / BB), dim3(256), 0, stream,
                       x0, Win, bin, bmid, bsl, wid, wtc, out);
}

// Round 11
// 304.064 us; speedup vs baseline: 1.7231x; 1.3087x over previous
//
#include <hip/hip_runtime.h>

// Problem constants
#define BTOT 16384
#define NI   16
#define HD   256
#define BB   4            // elements per block = waves per block
#define NMID 3
#define ASH  264          // h LDS row stride in bf16 (528B, 16B-aligned)
#define SLS  20           // slater scratch row stride (floats)
#define HALF_LOGFACT 15.3359295387f  // 0.5 * ln(16!)

typedef short  bf16x8 __attribute__((ext_vector_type(8)));
typedef float  f32x4  __attribute__((ext_vector_type(4)));
typedef const __attribute__((address_space(1))) unsigned int* as1p;
typedef __attribute__((address_space(3))) unsigned int* as3p;

__device__ __forceinline__ unsigned short f2bf(float f) {   // prep kernel only
    unsigned u = __builtin_bit_cast(unsigned, f);
    u += 0x7FFFu + ((u >> 16) & 1u);
    return (unsigned short)(u >> 16);
}
__device__ __forceinline__ unsigned cvt_pk_bf16(float lo, float hi) {
    unsigned d;
    asm("v_cvt_pk_bf16_f32 %0, %1, %2" : "=v"(d) : "v"(lo), "v"(hi));
    return d;   // d[15:0]=bf16(lo), d[31:16]=bf16(hi)
}
__device__ __forceinline__ float bflo(unsigned u) { return __builtin_bit_cast(float, u << 16); }
__device__ __forceinline__ float bfhi(unsigned u) { return __builtin_bit_cast(float, u & 0xFFFF0000u); }
__device__ __forceinline__ float bcast(float x, int lane) {   // uniform lane broadcast
    return __builtin_bit_cast(float,
        __builtin_amdgcn_readlane(__builtin_bit_cast(int, x), lane));
}
// tanh(x) = 1 - 2/(1 + 2^(x*2*log2(e))) : 5 VALU ops
__device__ __forceinline__ float tanh5(float x) {
    float z = __builtin_amdgcn_exp2f(x * 2.885390081777927f);
    return __builtin_fmaf(-2.0f, __builtin_amdgcn_rcpf(1.0f + z), 1.0f);
}
#define LGKM_BAR() do { asm volatile("s_waitcnt lgkmcnt(0)" ::: "memory"); \
    __builtin_amdgcn_s_barrier(); __builtin_amdgcn_sched_barrier(0); } while (0)

// ---- prep: chunked fragment-order weights (verified R6-R10).
// Chunk fc<48: (layer=fc>>4, ch=fc&15): dst[kg*128 + j*8 + kk] = Wmid[layer][8kg+kk][ch*16+j],
//   kg in [0,64). Chunk 48: Wsl, kg in [0,32), rest zero.
__global__ void prep_w(const float* __restrict__ Wmid, const float* __restrict__ Wsl,
                       unsigned short* __restrict__ wtc) {
    const int b = blockIdx.x;       // 0..48
    const int t = threadIdx.x;
    unsigned short* dst = wtc + (size_t)b * 8192;
    if (b < 48) {
        const int layer = b >> 4, ch = b & 15;
        const float* src = Wmid + (size_t)layer * (2 * HD * HD);
#pragma unroll 4
        for (int v = 0; v < 32; ++v) {
            int o = t * 32 + v;
            int kk = o & 7, j = (o >> 3) & 15, kg = o >> 7;
            dst[o] = f2bf(src[(8 * kg + kk) * HD + ch * 16 + j]);
        }
    } else {
#pragma unroll 4
        for (int v = 0; v < 32; ++v) {
            int o = t * 32 + v;
            int kk = o & 7, j = (o >> 3) & 15, kg = o >> 7;
            dst[o] = (kg < 32) ? f2bf(Wsl[(8 * kg + kk) * NI + j]) : (unsigned short)0;
        }
    }
}

struct __align__(16) SMem {
    unsigned short wt[2][4096];           // 16384 B: 2-ring of h-part W (kg<32)
    union {
        unsigned short h[BB * NI * ASH];  // 33792 B: bf16 h (in-place across layers)
        float slf[BB][NI * ASH / 2];      // per-element slater scratch (own region)
    } u;
    union {
        unsigned short gmgv[BB * HD];     // 2048 B: gm at layer top; gv(+bias) overwrites
        struct { float x0[BB * NI]; float gmean[BB]; } x;  // input phase only
    } v;
};
static_assert(sizeof(SMem) == 52224, "3 blocks/CU needs <= ~52.7KB");

__device__ __forceinline__ void stage_half(const unsigned short* __restrict__ wtc,
                                           unsigned short* dst_base, int fc, int tid) {
    const unsigned short* gsrc = wtc + (size_t)fc * 8192 + tid * 8;
    __builtin_amdgcn_global_load_lds((as1p)gsrc,          (as3p)(dst_base + tid * 8),        16, 0, 0);
    __builtin_amdgcn_global_load_lds((as1p)(gsrc + 2048), (as3p)(dst_base + tid * 8 + 2048), 16, 0, 0);
}

__global__ __launch_bounds__(256, 3)
void eqslater_mfma(const float* __restrict__ x0g,
                   const float* __restrict__ Win,
                   const float* __restrict__ bin,
                   const float* __restrict__ bmid,
                   const float* __restrict__ bsl,
                   const float* __restrict__ width,
                   const unsigned short* __restrict__ wtc,
                   float* __restrict__ out) {
    __shared__ SMem sm;
    const int tid = threadIdx.x;
    const int bbase = blockIdx.x * BB;
    const int e = tid >> 6;   // wave = element
    const int l = tid & 63;
    const int c = l & 15;     // h-row (B/C-col in transposed orientation)
    const int g = l >> 4;     // k-group; C rows 4g..4g+3 -> cols j = 16ch+4g+q
    const int j4 = 4 * g;

    // ---- prologue: stage chunk 0 (DMA completion not needed until chunk 0's vmcnt)
    stage_half(wtc, sm.wt[0], 0, tid);

    if (tid < BB * NI) sm.v.x.x0[tid] = x0g[bbase * NI + tid];
    LGKM_BAR();
    if (tid < BB) {
        float s = 0.f;
#pragma unroll
        for (int n = 0; n < NI; ++n) s += sm.v.x.x0[tid * NI + n];
        sm.v.x.gmean[tid] = s * 0.0625f;
    }
    LGKM_BAR();

    // ---- input layer: col-pair per thread, cvt_pk packed stores
    {
        const int p2 = tid & 127;            // cols 2p2, 2p2+1
        const int rh = tid >> 7;             // rows rh*32..rh*32+31
        const float w0a = Win[2 * p2],      w0b = Win[2 * p2 + 1];
        const float w1a = Win[HD + 2 * p2], w1b = Win[HD + 2 * p2 + 1];
        const float ba  = bin[2 * p2],      bb2 = bin[2 * p2 + 1];
#pragma unroll
        for (int half = 0; half < 2; ++half) {
            const int el = rh * 2 + half;
            const float gmv = sm.v.x.gmean[el];
            const float g1a = gmv * w1a + ba, g1b = gmv * w1b + bb2;
#pragma unroll 4
            for (int r = 0; r < NI; ++r) {
                float xv = sm.v.x.x0[el * NI + r];
                float f0 = tanh5(__builtin_fmaf(xv, w0a, g1a));
                float f1 = tanh5(__builtin_fmaf(xv, w0b, g1b));
                *(unsigned*)&sm.u.h[(el * NI + r) * ASH + 2 * p2] = cvt_pk_bf16(f0, f1);
            }
        }
    }
    LGKM_BAR();   // h visible; x0/gmean dead (chunk-0 DMA still in flight - OK)

    bf16x8 af[8], agm[8], bq2[8];

#pragma unroll 1
    for (int layer = 0; layer < NMID; ++layer) {
        // ---- gm: column means of own h -> gmgv[e] (wave-private write)
        {
            const int c0 = l * 4;
            float s0 = 0, s1 = 0, s2 = 0, s3 = 0;
#pragma unroll
            for (int r = 0; r < NI; ++r) {
                uint2 d = *(const uint2*)&sm.u.h[(e * NI + r) * ASH + c0];
                s0 += bflo(d.x); s1 += bfhi(d.x);
                s2 += bflo(d.y); s3 += bfhi(d.y);
            }
            uint2 o;
            o.x = cvt_pk_bf16(s0 * 0.0625f, s1 * 0.0625f);
            o.y = cvt_pk_bf16(s2 * 0.0625f, s3 * 0.0625f);
            *(uint2*)&sm.v.gmgv[e * HD + c0] = o;
        }
#pragma unroll
        for (int s = 0; s < 8; ++s)
            af[s] = *(const bf16x8*)&sm.u.h[(e * NI + c) * ASH + 32 * s + 8 * g];
        LGKM_BAR();   // gm of ALL elements visible
        // replicated-gm B frags (B col r = gm of element r&3) -> registers
#pragma unroll
        for (int s = 0; s < 8; ++s)
            agm[s] = *(const bf16x8*)&sm.v.gmgv[(c & 3) * HD + 32 * s + 8 * g];

        const float* bml = bmid + layer * HD;
        f32x4 avp = {0.f, 0.f, 0.f, 0.f};

#pragma unroll 1
        for (int ch = 0; ch < 16; ++ch) {
            const int fc = layer * 16 + ch;
            LGKM_BAR();   // gv(ch-1) visible; all waves done reading wt(fc-1)

            if (fc < 48) stage_half(wtc, sm.wt[(fc + 1) & 1], fc + 1, tid);
            __builtin_amdgcn_sched_barrier(0);

            // lagged epilogue ch-1 (covers DMA(fc) tail; pure DS+VALU)
            if (ch > 0) {
                const int jp = (ch - 1) * 16 + j4;
                unsigned short* hrow = &sm.u.h[(e * NI + c) * ASH + jp];
                uint2 gd = *(const uint2*)&sm.v.gmgv[e * HD + jp];
                uint2 hd2 = *(const uint2*)hrow;
                float f0 = tanh5(avp[0] + bflo(gd.x)) + bflo(hd2.x);
                float f1 = tanh5(avp[1] + bfhi(gd.x)) + bfhi(hd2.x);
                float f2 = tanh5(avp[2] + bflo(gd.y)) + bflo(hd2.y);
                float f3 = tanh5(avp[3] + bfhi(gd.y)) + bfhi(hd2.y);
                uint2 w;
                w.x = cvt_pk_bf16(f0, f1); w.y = cvt_pk_bf16(f2, f3);
                *(uint2*)hrow = w;
            }
            __builtin_amdgcn_sched_barrier(0);
            // counted wait: fc's DMA (oldest 2) done; stage(fc+1) stays in flight
            asm volatile("s_waitcnt vmcnt(2)" ::: "memory");
            __builtin_amdgcn_sched_barrier(0);

            const bool own = (ch >> 2) == e;
            float4 bsv;
            if (own) {   // gm-part W frags + bias from global (L2-hot)
                const unsigned short* gp = wtc + (size_t)fc * 8192 + c * 8 + g * 128;
#pragma unroll
                for (int t2 = 0; t2 < 8; ++t2)
                    bq2[t2] = *(const bf16x8*)(gp + (32 + 4 * t2) * 128);
                bsv = *(const float4*)&bml[ch * 16 + j4];
            }

            // h-part GEMM (transposed: A=W frag, B=h frag) -> C[j=16ch+4g+q][r=c]
            const unsigned short* wb = sm.wt[fc & 1];
            f32x4 p0 = {0.f,0.f,0.f,0.f}, p1 = {0.f,0.f,0.f,0.f};
#pragma unroll
            for (int s = 0; s < 4; ++s) {
                bf16x8 b0 = *(const bf16x8*)&wb[(8 * s     + g) * 128 + c * 8];
                bf16x8 b1 = *(const bf16x8*)&wb[(8 * s + 4 + g) * 128 + c * 8];
                p0 = __builtin_amdgcn_mfma_f32_16x16x32_bf16(b0, af[2 * s],     p0, 0, 0, 0);
                p1 = __builtin_amdgcn_mfma_f32_16x16x32_bf16(b1, af[2 * s + 1], p1, 0, 0, 0);
            }
            avp = p0 + p1;

            // rank-1 gm-GEMM: owner computes gvec(+bias) for ALL 4 elements
            if (own) {
                f32x4 q0 = {0.f,0.f,0.f,0.f}, q1 = {0.f,0.f,0.f,0.f};
#pragma unroll
                for (int s = 0; s < 4; ++s) {
                    q0 = __builtin_amdgcn_mfma_f32_16x16x32_bf16(bq2[2 * s],     agm[2 * s],     q0, 0, 0, 0);
                    q1 = __builtin_amdgcn_mfma_f32_16x16x32_bf16(bq2[2 * s + 1], agm[2 * s + 1], q1, 0, 0, 0);
                }
                f32x4 gq = q0 + q1;   // lane (g,c): gvec[el=c&3][j=16ch+4g+q]
                if (c < 4) {
                    uint2 w;
                    w.x = cvt_pk_bf16(gq[0] + bsv.x, gq[1] + bsv.y);
                    w.y = cvt_pk_bf16(gq[2] + bsv.z, gq[3] + bsv.w);
                    *(uint2*)&sm.v.gmgv[c * HD + ch * 16 + j4] = w;
                }
            }
        }
        LGKM_BAR();   // gv(15) visible
        {   // final epilogue of the layer
            const int jp = 240 + j4;
            unsigned short* hrow = &sm.u.h[(e * NI + c) * ASH + jp];
            uint2 gd = *(const uint2*)&sm.v.gmgv[e * HD + jp];
            uint2 hd2 = *(const uint2*)hrow;
            float f0 = tanh5(avp[0] + bflo(gd.x)) + bflo(hd2.x);
            float f1 = tanh5(avp[1] + bfhi(gd.x)) + bfhi(hd2.x);
            float f2 = tanh5(avp[2] + bflo(gd.y)) + bflo(hd2.y);
            float f3 = tanh5(avp[3] + bfhi(gd.y)) + bfhi(hd2.y);
            uint2 w;
            w.x = cvt_pk_bf16(f0, f1); w.y = cvt_pk_bf16(f2, f3);
            *(uint2*)hrow = w;
        }
        __builtin_amdgcn_sched_barrier(0);
    }

    // ---- slater head: chunk 48 in wt[0] (48&1==0)
#pragma unroll
    for (int s = 0; s < 8; ++s)
        af[s] = *(const bf16x8*)&sm.u.h[(e * NI + c) * ASH + 32 * s + 8 * g];
    asm volatile("s_waitcnt vmcnt(0) lgkmcnt(0)" ::: "memory");
    __builtin_amdgcn_s_barrier();
    __builtin_amdgcn_sched_barrier(0);
    {
        const unsigned short* wb = sm.wt[0];
        f32x4 a0 = {0.f,0.f,0.f,0.f}, a1 = {0.f,0.f,0.f,0.f};
#pragma unroll
        for (int s = 0; s < 4; ++s) {
            bf16x8 b0 = *(const bf16x8*)&wb[(8 * s     + g) * 128 + c * 8];
            bf16x8 b1 = *(const bf16x8*)&wb[(8 * s + 4 + g) * 128 + c * 8];
            a0 = __builtin_amdgcn_mfma_f32_16x16x32_bf16(b0, af[2 * s],     a0, 0, 0, 0);
            a1 = __builtin_amdgcn_mfma_f32_16x16x32_bf16(b1, af[2 * s + 1], a1, 0, 0, 0);
        }
        f32x4 sv = a0 + a1;   // lane (g,c): sl[row r=c][m=4g+q]
        const float4 bsv = *(const float4*)&bsl[j4];
        float* slp = &sm.u.slf[e][0];   // own-element region; own h now dead
        float4 o;
        o.x = sv[0] + bsv.x; o.y = sv[1] + bsv.y;
        o.z = sv[2] + bsv.z; o.w = sv[3] + bsv.w;
        *(float4*)&slp[c * SLS + j4] = o;
    }

    // ---- per-wave slogdet: swap-free LU w/ partial pivoting
    {
        const float* slp = &sm.u.slf[e][0];
        const int i = c;   // row, 4x duplicated across lanes
        float M[16];
#pragma unroll
        for (int jj = 0; jj < 4; ++jj) {
            float4 vv = *(const float4*)&slp[i * SLS + 4 * jj];
            M[4 * jj] = vv.x; M[4 * jj + 1] = vv.y; M[4 * jj + 2] = vv.z; M[4 * jj + 3] = vv.w;
        }

        int elim = 0;              // this lane's row already chosen as pivot
        unsigned chosen = 0;       // uniform: bitmask of chosen rows
        int invcnt = 0;            // uniform: inversion count of pivot sequence
        float dsign = 1.f, logabs = 0.f;
#pragma unroll
        for (int k = 0; k < 16; ++k) {
            float myv = elim ? -1.f : __builtin_fabsf(M[k]);
            float maxv = myv;
#pragma unroll
            for (int off = 8; off > 0; off >>= 1)
                maxv = fmaxf(maxv, __shfl_xor(maxv, off));
            unsigned long long bal = __ballot(myv == maxv);
            const int p = (__ffsll((long long)bal) - 1) & 15;   // lowest row w/ max

            invcnt += __popc(chosen >> (p + 1));   // rows chosen earlier with index > p
            chosen |= 1u << p;
            if (i == p) elim = 1;                  // pivot row finalized (pre-update)

            float piv = bcast(M[k], p);
            // NaN guard (singular matrix): finite logabs, no 0/0 poison.
            float ap = fmaxf(__builtin_fabsf(piv), 1e-35f);
            logabs += __logf(ap);
            if (piv < 0.f) dsign = -dsign;
            float spiv = __builtin_copysignf(ap, piv);
            float mi = __fdividef(M[k], spiv);
#pragma unroll
            for (int j = k + 1; j < 16; ++j) {
                float pr = bcast(M[j], p);
                if (!elim) M[j] = __builtin_fmaf(-mi, pr, M[j]);
            }
        }
        if (invcnt & 1) dsign = -dsign;

        float xv = (l < NI) ? x0g[(bbase + e) * NI + l] : 0.f;
        float sq = xv * xv;
#pragma unroll
        for (int off = 8; off > 0; off >>= 1) sq += __shfl_xor(sq, off);

        if (l == 0) {
            out[bbase + e] = dsign;
            out[BTOT + bbase + e] = logabs - HALF_LOGFACT - width[0] * sq;
        }
    }
}

extern "C" void kernel_launch(void* const* d_in, const int* in_sizes, int n_in,
                              void* d_out, int out_size, void* d_ws, size_t ws_size,
                              hipStream_t stream) {
    const float* x0   = (const float*)d_in[0];
    const float* Win  = (const float*)d_in[1];
    const float* bin  = (const float*)d_in[2];
    const float* Wmid = (const float*)d_in[3];
    const float* bmid = (const float*)d_in[4];
    const float* Wsl  = (const float*)d_in[5];
    const float* bsl  = (const float*)d_in[6];
    const float* wid  = (const float*)d_in[7];
    float* out = (float*)d_out;

    unsigned short* wtc = (unsigned short*)d_ws;   // 49 * 16384 B = 802816 B

    hipLaunchKernelGGL(prep_w, dim3(49), dim3(256), 0, stream, Wmid, Wsl, wtc);
    hipLaunchKernelGGL(eqslater_mfma, dim3(BTOT / BB), dim3(256), 0, stream,
                       x0, Win, bin, bmid, bsl, wid, wtc, out);
}